// Round 9
// baseline (574.388 us; speedup 1.0000x reference)
//
#include <hip/hip_runtime.h>
#include <hip/hip_bf16.h>

// Problem constants
#define S_LEN 2048
#define HID 4096
#define NH 32
#define NKV 8
#define HD 128
#define LDQKV 6144   // fused QKV output: cols [0,4096)=Q, [4096,5120)=K, [5120,6144)=V

typedef __bf16 bf16x8 __attribute__((ext_vector_type(8)));
typedef __bf16 bf16x4 __attribute__((ext_vector_type(4)));
typedef float f32x4 __attribute__((ext_vector_type(4)));

// async global->LDS, 16B per lane (HW: wave-uniform LDS base + lane*16)
#define GLD16(gp, lp)                                                                   \
    __builtin_amdgcn_global_load_lds((const __attribute__((address_space(1))) void*)(gp), \
                                     (__attribute__((address_space(3))) void*)(lp), 16, 0, 0)

// ---------------------------------------------------------------------------
__global__ void cast_bf16_kernel(const float* __restrict__ x, __bf16* __restrict__ y, int n) {
    int i = (blockIdx.x * blockDim.x + threadIdx.x) * 4;
    if (i < n) {
        float4 v = *reinterpret_cast<const float4*>(x + i);
        bf16x4 o;
        o.x = (__bf16)v.x; o.y = (__bf16)v.y; o.z = (__bf16)v.z; o.w = (__bf16)v.w;
        *reinterpret_cast<bf16x4*>(y + i) = o;
    }
}

// ---------------------------------------------------------------------------
// 64x64 vectorized transpose+cast+scale: W [K][N] fp32 -> WT [N][K] bf16*sc
// ---------------------------------------------------------------------------
__global__ __launch_bounds__(256) void transpose_cast64(const float* __restrict__ W,
                                                        __bf16* __restrict__ WT,
                                                        int K, int N, float sc) {
    __shared__ float tile[64][65];
    int n0 = blockIdx.x * 64, k0 = blockIdx.y * 64;
    int tx = threadIdx.x & 15, ty = threadIdx.x >> 4;
#pragma unroll
    for (int i = 0; i < 4; i++) {
        float4 v = *reinterpret_cast<const float4*>(&W[(size_t)(k0 + ty + i * 16) * N + n0 + tx * 4]);
        tile[ty + i * 16][tx * 4 + 0] = v.x;
        tile[ty + i * 16][tx * 4 + 1] = v.y;
        tile[ty + i * 16][tx * 4 + 2] = v.z;
        tile[ty + i * 16][tx * 4 + 3] = v.w;
    }
    __syncthreads();
#pragma unroll
    for (int i = 0; i < 4; i++) {
        int n = ty + i * 16;
        bf16x4 o;
#pragma unroll
        for (int jj = 0; jj < 4; jj++) o[jj] = (__bf16)(tile[tx * 4 + jj][n] * sc);
        *reinterpret_cast<bf16x4*>(&WT[(size_t)(n0 + n) * K + k0 + tx * 4]) = o;
    }
}

// ---------------------------------------------------------------------------
// fused wq/wk/wv transpose into one launch (all K=4096 rows): bx selects matrix
// ---------------------------------------------------------------------------
__global__ __launch_bounds__(256) void transpose_qkv_kernel(const float* __restrict__ Wq,
                                                            const float* __restrict__ Wk,
                                                            const float* __restrict__ Wv,
                                                            __bf16* __restrict__ WT, float scq) {
    __shared__ float tile[64][65];
    int bx = blockIdx.x;  // 0..95
    const float* W; int N; int nbase; size_t obase; float sc;
    if (bx < 64)      { W = Wq; N = 4096; nbase = bx * 64;        obase = 0;                  sc = scq; }
    else if (bx < 80) { W = Wk; N = 1024; nbase = (bx - 64) * 64; obase = (size_t)4096 * HID; sc = 1.f; }
    else              { W = Wv; N = 1024; nbase = (bx - 80) * 64; obase = (size_t)5120 * HID; sc = 1.f; }
    int k0 = blockIdx.y * 64;
    int tx = threadIdx.x & 15, ty = threadIdx.x >> 4;
#pragma unroll
    for (int i = 0; i < 4; i++) {
        float4 v = *reinterpret_cast<const float4*>(&W[(size_t)(k0 + ty + i * 16) * N + nbase + tx * 4]);
        tile[ty + i * 16][tx * 4 + 0] = v.x;
        tile[ty + i * 16][tx * 4 + 1] = v.y;
        tile[ty + i * 16][tx * 4 + 2] = v.z;
        tile[ty + i * 16][tx * 4 + 3] = v.w;
    }
    __syncthreads();
#pragma unroll
    for (int i = 0; i < 4; i++) {
        int n = ty + i * 16;
        bf16x4 o;
#pragma unroll
        for (int jj = 0; jj < 4; jj++) o[jj] = (__bf16)(tile[tx * 4 + jj][n] * sc);
        *reinterpret_cast<bf16x4*>(&WT[obase + (size_t)(nbase + n) * HID + k0 + tx * 4]) = o;
    }
}

// ---------------------------------------------------------------------------
// strided bf16 transpose with sigma-permuted output columns (per 64-group):
// V [R][C] (ld=ldin) -> VT [C][perm(R)] (ld=ldout), perm(s)=(s&15)*4+(s>>4&3)
// Matches the packed P-store position layout in attn_kernel.
// ---------------------------------------------------------------------------
__global__ void transpose_vperm_kernel(const __bf16* __restrict__ V, int ldin,
                                       __bf16* __restrict__ VT, int ldout) {
    __shared__ __bf16 tile[32][33];
    int bx = blockIdx.x;  // over C/32 (d dim)
    int by = blockIdx.y;  // over R/32 (seq dim)
    int tx = threadIdx.x;
    int ty = threadIdx.y;
#pragma unroll
    for (int i = 0; i < 4; i++)
        tile[ty + i * 8][tx] = V[(size_t)(by * 32 + ty + i * 8) * ldin + bx * 32 + tx];
    __syncthreads();
    int s = by * 32 + tx;
    int sp = (s & ~63) | ((s & 15) << 2) | ((s >> 4) & 3);
#pragma unroll
    for (int i = 0; i < 4; i++)
        VT[(size_t)(bx * 32 + ty + i * 8) * ldout + sp] = tile[tx][ty + i * 8];
}

// ---------------------------------------------------------------------------
// NT GEMM: C = A[M,K] * BT[N,K]^T, bf16 in, fp32 acc. 128x128 tile, BK=64
// (half the barriers of the BK=32 m97 form; LDS 32 KB keeps 3 blocks/CU).
// ---------------------------------------------------------------------------
template <typename OUT_T>
__global__ __launch_bounds__(256) void gemm_bt_kernel(const __bf16* __restrict__ A, int lda,
                                                      const __bf16* __restrict__ BT, int ldb,
                                                      OUT_T* __restrict__ C, int ldc, int K) {
    __shared__ __bf16 As[128 * 64];
    __shared__ __bf16 Bs[128 * 64];
    int n0 = blockIdx.x * 128;
    int m0 = blockIdx.y * 128;
    int tid = threadIdx.x;
    int wave = tid >> 6, lane = tid & 63, quad = lane >> 4, l16 = lane & 15;
    int wm = (wave >> 1) * 64, wn = (wave & 1) * 64;

    f32x4 acc[4][4] = {};

    for (int kb = 0; kb < K; kb += 64) {
        __syncthreads();
#pragma unroll
        for (int q = 0; q < 4; q++) {
            int j = tid + q * 256;              // 1024 chunks of 16B per matrix
            int row = j >> 3, col8 = (j & 7) * 8;
            GLD16(&A[(size_t)(m0 + row) * lda + kb + col8], &As[j * 8]);
            GLD16(&BT[(size_t)(n0 + row) * ldb + kb + col8], &Bs[j * 8]);
        }
        __syncthreads();
#pragma unroll
        for (int ks = 0; ks < 2; ks++) {
            bf16x8 af[4], bfr[4];
#pragma unroll
            for (int mt = 0; mt < 4; mt++)
                af[mt] = *reinterpret_cast<const bf16x8*>(
                    &As[(wm + mt * 16 + l16) * 64 + ks * 32 + quad * 8]);
#pragma unroll
            for (int nt = 0; nt < 4; nt++)
                bfr[nt] = *reinterpret_cast<const bf16x8*>(
                    &Bs[(wn + nt * 16 + l16) * 64 + ks * 32 + quad * 8]);
#pragma unroll
            for (int mt = 0; mt < 4; mt++)
#pragma unroll
                for (int nt = 0; nt < 4; nt++)
                    acc[mt][nt] = __builtin_amdgcn_mfma_f32_16x16x32_bf16(af[mt], bfr[nt],
                                                                          acc[mt][nt], 0, 0, 0);
        }
    }

#pragma unroll
    for (int mt = 0; mt < 4; mt++)
#pragma unroll
        for (int nt = 0; nt < 4; nt++)
#pragma unroll
            for (int r = 0; r < 4; r++) {
                int row = m0 + wm + mt * 16 + quad * 4 + r;
                int col = n0 + wn + nt * 16 + l16;
                C[(size_t)row * ldc + col] = (OUT_T)acc[mt][nt][r];
            }
}

// ---------------------------------------------------------------------------
// Flash attention v8 (causal, GQA) — shift-free softmax, MFMA row-sums,
// 2 q-heads/block, split-KV CS=16, PACKED P-stores: P positions are
// sigma-permuted (pos = 4*l16 + n) so each lane writes one bf16x4 per row;
// V^T columns carry the same permutation (transpose_vperm_kernel).
// ---------------------------------------------------------------------------
__global__ __launch_bounds__(256) void attn_kernel(const __bf16* __restrict__ QKV,
                                                   const __bf16* __restrict__ VT,
                                                   __bf16* __restrict__ Ao,
                                                   __bf16* __restrict__ Opart,
                                                   float* __restrict__ Lp) {
    __shared__ __bf16 Ks[64 * 128];      // K tile [64 kv][128 d], chunk-swizzled
    __shared__ __bf16 Vs[128 * 64];      // V^T tile [128 d][64 pos], chunk-swizzled
    __shared__ __bf16 Pl[4][2][16 * 72]; // per-wave, per-head P (+8 pad)
    int x = blockIdx.x;                  // chunk-slot, heavy-first mapping
    int qt, c;
    if (x < 32) { qt = 31 - (x >> 1); c = x & 1; }   // qt 16..31, 2 chunks
    else        { qt = 47 - x;        c = 0;     }   // qt 15..0, 1 chunk
    int hp = blockIdx.y;                 // head pair 0..15
    int kvh = hp >> 1;
    int h0 = kvh * 4 + (hp & 1) * 2;     // absolute heads h0, h0+1
    int t0 = c ? 16 : 0;
    int t1 = c ? qt : min(qt, 15);
    int tid = threadIdx.x;
    int wave = tid >> 6, lane = tid & 63, quad = lane >> 4, l16 = lane & 15;
    int wq = qt * 64 + wave * 16;        // this wave's 16 q-rows
    const __bf16* Kb = QKV + HID + (size_t)kvh * HD;
    const __bf16* Vt = VT + (size_t)kvh * HD * S_LEN;

    // Q fragments for both heads (pre-scaled by scale*log2e via Wq)
    bf16x8 qf[2][4];
#pragma unroll
    for (int h = 0; h < 2; h++)
#pragma unroll
        for (int ks = 0; ks < 4; ks++)
            qf[h][ks] = *reinterpret_cast<const bf16x8*>(
                &QKV[(size_t)(wq + l16) * LDQKV + (h0 + h) * HD + ks * 32 + quad * 8]);

    bf16x8 ones;
#pragma unroll
    for (int j = 0; j < 8; j++) ones[j] = (__bf16)1.0f;

    f32x4 acc_o[2][8] = {};
    f32x4 lacc[2] = {};

    for (int t = t0; t <= t1; t++) {
        int kv0 = t << 6;
        bool diag = (t == qt);
        __syncthreads();  // previous tile's LDS reads done
        // ---- stage K tile: 1024 chunks of 16B, source-side XOR swizzle
#pragma unroll
        for (int i = 0; i < 4; i++) {
            int cc = i * 256 + tid;
            int row = cc >> 4, sub = cc & 15;
            int col8 = sub ^ (row & 15);
            GLD16(&Kb[(size_t)(kv0 + row) * LDQKV + col8 * 8], &Ks[cc * 8]);
        }
        // ---- stage V^T tile (permuted columns): 1024 chunks of 16B
#pragma unroll
        for (int i = 0; i < 4; i++) {
            int cc = i * 256 + tid;
            int row = cc >> 3, sub = cc & 7;
            int col8 = sub ^ (row & 7);
            GLD16(&Vt[(size_t)row * S_LEN + kv0 + col8 * 8], &Vs[cc * 8]);
        }
        __syncthreads();  // drains vmcnt + barrier

        // ---- S = Q K^T for both heads (kf shared)
        f32x4 sacc[2][4] = {};
#pragma unroll
        for (int ks = 0; ks < 4; ks++) {
            bf16x8 kf[4];
#pragma unroll
            for (int n = 0; n < 4; n++) {
                int row = n * 16 + l16;
                int sub = (ks * 4 + quad) ^ l16;
                kf[n] = *reinterpret_cast<const bf16x8*>(&Ks[row * 128 + sub * 8]);
            }
#pragma unroll
            for (int n = 0; n < 4; n++) {
                sacc[0][n] = __builtin_amdgcn_mfma_f32_16x16x32_bf16(qf[0][ks], kf[n],
                                                                     sacc[0][n], 0, 0, 0);
                sacc[1][n] = __builtin_amdgcn_mfma_f32_16x16x32_bf16(qf[1][ks], kf[n],
                                                                     sacc[1][n], 0, 0, 0);
            }
        }
        // ---- shift-free softmax: P = exp2(S), packed bf16x4 store per row
#pragma unroll
        for (int h = 0; h < 2; h++) {
            __bf16* Pw = Pl[wave][h];
#pragma unroll
            for (int r = 0; r < 4; r++) {
                int row = wq + quad * 4 + r;
                bf16x4 pk;
#pragma unroll
                for (int n = 0; n < 4; n++) {
                    float v = sacc[h][n][r];
                    if (diag) {
                        int col = kv0 + n * 16 + l16;
                        if (col > row) v = -1e30f;  // causal mask (diag tile only)
                    }
                    pk[n] = (__bf16)__builtin_amdgcn_exp2f(v);
                }
                // position 4*l16+n  <->  logical kv = n*16+l16 (sigma)
                *reinterpret_cast<bf16x4*>(&Pw[(quad * 4 + r) * 72 + l16 * 4]) = pk;
            }
        }
        // ---- O += P V ; l += P * ones (row-sums via MFMA)
#pragma unroll
        for (int ks = 0; ks < 2; ks++) {
            bf16x8 pf0 = *reinterpret_cast<const bf16x8*>(
                &Pl[wave][0][l16 * 72 + ks * 32 + quad * 8]);
            bf16x8 pf1 = *reinterpret_cast<const bf16x8*>(
                &Pl[wave][1][l16 * 72 + ks * 32 + quad * 8]);
            lacc[0] = __builtin_amdgcn_mfma_f32_16x16x32_bf16(pf0, ones, lacc[0], 0, 0, 0);
            lacc[1] = __builtin_amdgcn_mfma_f32_16x16x32_bf16(pf1, ones, lacc[1], 0, 0, 0);
#pragma unroll
            for (int dn = 0; dn < 8; dn++) {
                int row = dn * 16 + l16;
                int sub = (ks * 4 + quad) ^ (row & 7);
                bf16x8 vf = *reinterpret_cast<const bf16x8*>(&Vs[row * 64 + sub * 8]);
                acc_o[0][dn] = __builtin_amdgcn_mfma_f32_16x16x32_bf16(pf0, vf,
                                                                       acc_o[0][dn], 0, 0, 0);
                acc_o[1][dn] = __builtin_amdgcn_mfma_f32_16x16x32_bf16(pf1, vf,
                                                                       acc_o[1][dn], 0, 0, 0);
            }
        }
    }

    // ---- epilogue
    if (qt < 16) {
#pragma unroll
        for (int h = 0; h < 2; h++) {
            float rl[4];
#pragma unroll
            for (int r = 0; r < 4; r++) rl[r] = 1.0f / lacc[h][r];
#pragma unroll
            for (int dn = 0; dn < 8; dn++)
#pragma unroll
                for (int r = 0; r < 4; r++) {
                    int row = wq + quad * 4 + r;
                    int col = (h0 + h) * HD + dn * 16 + l16;
                    Ao[(size_t)row * HID + col] = (__bf16)(acc_o[h][dn][r] * rl[r]);
                }
        }
    } else {
        int s = (qt - 16) * 2 + c;
#pragma unroll
        for (int h = 0; h < 2; h++) {
            size_t base = ((size_t)(h0 + h) * 32 + s) * 64 + wave * 16;
#pragma unroll
            for (int dn = 0; dn < 8; dn++)
#pragma unroll
                for (int r = 0; r < 4; r++)
                    Opart[(base + quad * 4 + r) * 128 + dn * 16 + l16] =
                        (__bf16)acc_o[h][dn][r];
            if (l16 == 0) {
#pragma unroll
                for (int r = 0; r < 4; r++)
                    Lp[base + quad * 4 + r] = lacc[h][r];
            }
        }
    }
}

// ---------------------------------------------------------------------------
// combine two chunks (qt >= 16): O = (O0 + O1) / (l0 + l1)
// ---------------------------------------------------------------------------
__global__ __launch_bounds__(256) void attn_combine(const __bf16* __restrict__ Opart,
                                                    const float* __restrict__ Lp,
                                                    __bf16* __restrict__ Ao) {
    int qt = 16 + (int)blockIdx.x;  // 16..31
    int h = blockIdx.y;
    int tid = threadIdx.x;
    size_t b0 = ((size_t)h * 32 + (qt - 16) * 2) * 64;
    size_t b1 = b0 + 64;
#pragma unroll 4
    for (int i = 0; i < 32; i++) {
        int el = i * 256 + tid;
        int rl = el >> 7, col = el & 127;
        float l = Lp[b0 + rl] + Lp[b1 + rl];
        float O = (float)Opart[(b0 + rl) * 128 + col] + (float)Opart[(b1 + rl) * 128 + col];
        int row = qt * 64 + rl;
        Ao[(size_t)row * HID + h * HD + col] = (__bf16)(O / l);
    }
}

// ---------------------------------------------------------------------------
extern "C" void kernel_launch(void* const* d_in, const int* in_sizes, int n_in,
                              void* d_out, int out_size, void* d_ws, size_t ws_size,
                              hipStream_t stream) {
    const float* hs = (const float*)d_in[0];
    // d_in[1] = attention_mask (pure causal; applied analytically)
    const float* wq = (const float*)d_in[2];
    const float* wk = (const float*)d_in[3];
    const float* wv = (const float*)d_in[4];
    const float* wo = (const float*)d_in[5];
    float* out = (float*)d_out;

    char* ws = (char*)d_ws;
    // workspace (92 MB with reuse)
    __bf16* WqkvT = (__bf16*)(ws + (size_t)0);          // 48 MB [6144][4096]; reused for WoT
    __bf16* Opart = (__bf16*)(ws + (size_t)0);          // 17 MB attn partials (weight window,
    float*  Lp    = (float*)(ws + ((size_t)20 << 20));  // 0.3 MB  dead during attention)
    __bf16* Xb    = (__bf16*)(ws + ((size_t)48 << 20)); // 16 MB [2048][4096]; reused for attn out
    __bf16* QKV   = (__bf16*)(ws + ((size_t)64 << 20)); // 24 MB [2048][6144]
    __bf16* VTg   = (__bf16*)(ws + ((size_t)88 << 20)); //  4 MB [1024][2048]
    __bf16* Ab    = Xb;

    const int nX = S_LEN * HID;  // 8M
    const float SC2 = 0.12751743f;  // (1/sqrt(128)) * log2(e), folded into Wq

    // 1) cast hidden to bf16
    cast_bf16_kernel<<<nX / 4 / 256, 256, 0, stream>>>(hs, Xb, nX);
    // 2) fused W_{q,k,v}^T in ONE launch (Wq pre-scaled into exp2 domain)
    transpose_qkv_kernel<<<dim3(96, 64), 256, 0, stream>>>(wq, wk, wv, WqkvT, SC2);
    // 3) one fused QKV GEMM: [2048][6144]
    gemm_bt_kernel<__bf16><<<dim3(LDQKV / 128, S_LEN / 128), 256, 0, stream>>>(
        Xb, HID, WqkvT, HID, QKV, LDQKV, HID);
    // 4) V^T (sigma-permuted columns) for PV B-operand
    transpose_vperm_kernel<<<dim3(32, 64), dim3(32, 8), 0, stream>>>(
        QKV + 5120, LDQKV, VTg, S_LEN);
    // 5) flash attention + combine
    attn_kernel<<<dim3(48, 16), 256, 0, stream>>>(QKV, VTg, Ab, Opart, Lp);
    attn_combine<<<dim3(16, 32), 256, 0, stream>>>(Opart, Lp, Ab);
    // 6) out = Ab @ WoT^T (fp32). WoT reuses WqkvT space (partials dead now).
    transpose_cast64<<<dim3(64, 64), 256, 0, stream>>>(wo, WqkvT, HID, HID, 1.0f);
    gemm_bt_kernel<float><<<dim3(HID / 128, S_LEN / 128), 256, 0, stream>>>(
        Ab, HID, WqkvT, HID, out, HID, HID);
}